// Round 1
// baseline (2169.975 us; speedup 1.0000x reference)
//
#include <hip/hip_runtime.h>
#include <math.h>
#include <stdint.h>

#define L_TOK 4096
#define E_DIM 1024
#define K_DIM 1024
#define H4    4096
#define V_DIM 50257
#define V_PAD 50304   // 393 * 128

typedef __bf16 bf16x8 __attribute__((ext_vector_type(8)));
typedef float  f32x4  __attribute__((ext_vector_type(4)));

__device__ __forceinline__ unsigned short f2bf(float f) {
    unsigned u = __builtin_bit_cast(unsigned, f);
    u += 0x7fffu + ((u >> 16) & 1u);        // round-to-nearest-even
    return (unsigned short)(u >> 16);
}

__device__ __forceinline__ float sigm(float x) { return 1.f / (1.f + __expf(-x)); }

// ---------------- prep kernels ----------------

// W_ih fp32 [4096*1024] -> bf16 bits
__global__ void cvt_wih(const float* __restrict__ src, unsigned short* __restrict__ dst) {
    int i = (blockIdx.x * 256 + threadIdx.x) * 4;
    float4 v = *(const float4*)(src + i);
    ushort4 o;
    o.x = f2bf(v.x); o.y = f2bf(v.y); o.z = f2bf(v.z); o.w = f2bf(v.w);
    *(ushort4*)(dst + i) = o;
}

// x[l] = bf16(emb[sentence[l]])
__global__ void gather_x(const int* __restrict__ sent, const float* __restrict__ emb,
                         unsigned short* __restrict__ dst) {
    int l = blockIdx.x, t = threadIdx.x;
    int tok = sent[l];
    float4 v = *(const float4*)(emb + (size_t)tok * E_DIM + t * 4);
    ushort4 o;
    o.x = f2bf(v.x); o.y = f2bf(v.y); o.z = f2bf(v.z); o.w = f2bf(v.w);
    *(ushort4*)(dst + (size_t)l * E_DIM + t * 4) = o;
}

// W_out fp32 [V][1024] -> bf16 [V_PAD][1024], pad rows zeroed
__global__ void cvt_wout(const float* __restrict__ src, unsigned short* __restrict__ dst) {
    int row = blockIdx.x, t = threadIdx.x;
    ushort4 o;
    if (row < V_DIM) {
        float4 v = *(const float4*)(src + (size_t)row * K_DIM + t * 4);
        o.x = f2bf(v.x); o.y = f2bf(v.y); o.z = f2bf(v.z); o.w = f2bf(v.w);
    } else {
        o.x = o.y = o.z = o.w = 0;
    }
    *(ushort4*)(dst + (size_t)row * K_DIM + t * 4) = o;
}

// ---------------- GEMM 1: gates = x @ W_ih^T + b_ih + b_hh ----------------
// A [4096][1024] bf16, B [4096][1024] bf16 (K-major both). Skips f-gate col tiles.
__global__ __launch_bounds__(256) void gemm_gates(
    const unsigned short* __restrict__ A, const unsigned short* __restrict__ B,
    const float* __restrict__ b_ih, const float* __restrict__ b_hh,
    float* __restrict__ gates) {
    __shared__ unsigned short As[128 * 32];
    __shared__ unsigned short Bs[128 * 32];
    const int tid = threadIdx.x;
    const int wave = tid >> 6, lane = tid & 63;
    const int l15 = lane & 15, quad = lane >> 4;
    const int wr = wave >> 1, wc = wave & 1;
    const int m0 = blockIdx.x * 128;
    const int ct = blockIdx.y;                       // 0..23 -> skip tiles 8..15 (f gate)
    const int n0 = (ct < 8 ? ct : ct + 8) * 128;

    f32x4 acc[4][4];
#pragma unroll
    for (int mi = 0; mi < 4; ++mi)
#pragma unroll
        for (int ni = 0; ni < 4; ++ni) {
            f32x4 z = {0.f, 0.f, 0.f, 0.f};
            acc[mi][ni] = z;
        }

    for (int kk = 0; kk < K_DIM; kk += 32) {
#pragma unroll
        for (int j = 0; j < 2; ++j) {
            int e = j * 256 + tid;                   // octet index (8 bf16 = 16B)
            int r = e >> 2, c = (e & 3) << 3;
            const unsigned short* ga = A + (size_t)(m0 + r) * K_DIM + kk + c;
            const unsigned short* gb = B + (size_t)(n0 + r) * K_DIM + kk + c;
            unsigned short* la = &As[(size_t)(e & ~63) * 8];   // wave-uniform base
            unsigned short* lb = &Bs[(size_t)(e & ~63) * 8];
            __builtin_amdgcn_global_load_lds((const __attribute__((address_space(1))) void*)ga,
                                             (__attribute__((address_space(3))) void*)la, 16, 0, 0);
            __builtin_amdgcn_global_load_lds((const __attribute__((address_space(1))) void*)gb,
                                             (__attribute__((address_space(3))) void*)lb, 16, 0, 0);
        }
        __syncthreads();
        bf16x8 af[4], bfr[4];
#pragma unroll
        for (int mi = 0; mi < 4; ++mi)
            af[mi] = *(const bf16x8*)&As[(wr * 64 + mi * 16 + l15) * 32 + quad * 8];
#pragma unroll
        for (int ni = 0; ni < 4; ++ni)
            bfr[ni] = *(const bf16x8*)&Bs[(wc * 64 + ni * 16 + l15) * 32 + quad * 8];
#pragma unroll
        for (int mi = 0; mi < 4; ++mi)
#pragma unroll
            for (int ni = 0; ni < 4; ++ni)
                acc[mi][ni] = __builtin_amdgcn_mfma_f32_16x16x32_bf16(af[mi], bfr[ni], acc[mi][ni], 0, 0, 0);
        __syncthreads();
    }

#pragma unroll
    for (int ni = 0; ni < 4; ++ni) {
        int n = n0 + wc * 64 + ni * 16 + l15;
        float bias = b_ih[n] + b_hh[n];
#pragma unroll
        for (int mi = 0; mi < 4; ++mi) {
            int mb = m0 + wr * 64 + mi * 16 + quad * 4;
#pragma unroll
            for (int r = 0; r < 4; ++r)
                gates[(size_t)(mb + r) * H4 + n] = acc[mi][ni][r] + bias;
        }
    }
}

// ---------------- LSTM elementwise: h = sig(o)*tanh(sig(i)*tanh(g)) ----------------
__global__ void lstm_ew(const float* __restrict__ gates, unsigned short* __restrict__ h) {
    int l = blockIdx.x, t = threadIdx.x;
    const float4 gi = *(const float4*)(gates + (size_t)l * H4 + t * 4);
    const float4 gg = *(const float4*)(gates + (size_t)l * H4 + 2048 + t * 4);
    const float4 go = *(const float4*)(gates + (size_t)l * H4 + 3072 + t * 4);
    ushort4 o;
    o.x = f2bf(sigm(go.x) * tanhf(sigm(gi.x) * tanhf(gg.x)));
    o.y = f2bf(sigm(go.y) * tanhf(sigm(gi.y) * tanhf(gg.y)));
    o.z = f2bf(sigm(go.z) * tanhf(sigm(gi.z) * tanhf(gg.z)));
    o.w = f2bf(sigm(go.w) * tanhf(sigm(gi.w) * tanhf(gg.w)));
    *(ushort4*)(h + (size_t)l * 1024 + t * 4) = o;
}

// ---------------- GEMM 2: logits = h @ W_out^T + b_out, fused exp-sum ----------------
__global__ __launch_bounds__(256) void gemm_logits(
    const unsigned short* __restrict__ A,      // h bf16 [4096][1024]
    const unsigned short* __restrict__ B,      // W_out bf16 [V_PAD][1024]
    const float* __restrict__ b_out,
    float* __restrict__ out,                   // [4096][V_DIM]
    float* __restrict__ rowsum) {
    __shared__ unsigned short As[128 * 32];
    __shared__ unsigned short Bs[128 * 32];
    const int tid = threadIdx.x;
    const int wave = tid >> 6, lane = tid & 63;
    const int l15 = lane & 15, quad = lane >> 4;
    const int wr = wave >> 1, wc = wave & 1;
    const int m0 = blockIdx.x * 128;
    const int n0 = blockIdx.y * 128;

    f32x4 acc[4][4];
#pragma unroll
    for (int mi = 0; mi < 4; ++mi)
#pragma unroll
        for (int ni = 0; ni < 4; ++ni) {
            f32x4 z = {0.f, 0.f, 0.f, 0.f};
            acc[mi][ni] = z;
        }

    for (int kk = 0; kk < K_DIM; kk += 32) {
#pragma unroll
        for (int j = 0; j < 2; ++j) {
            int e = j * 256 + tid;
            int r = e >> 2, c = (e & 3) << 3;
            const unsigned short* ga = A + (size_t)(m0 + r) * K_DIM + kk + c;
            const unsigned short* gb = B + (size_t)(n0 + r) * K_DIM + kk + c;
            unsigned short* la = &As[(size_t)(e & ~63) * 8];
            unsigned short* lb = &Bs[(size_t)(e & ~63) * 8];
            __builtin_amdgcn_global_load_lds((const __attribute__((address_space(1))) void*)ga,
                                             (__attribute__((address_space(3))) void*)la, 16, 0, 0);
            __builtin_amdgcn_global_load_lds((const __attribute__((address_space(1))) void*)gb,
                                             (__attribute__((address_space(3))) void*)lb, 16, 0, 0);
        }
        __syncthreads();
        bf16x8 af[4], bfr[4];
#pragma unroll
        for (int mi = 0; mi < 4; ++mi)
            af[mi] = *(const bf16x8*)&As[(wr * 64 + mi * 16 + l15) * 32 + quad * 8];
#pragma unroll
        for (int ni = 0; ni < 4; ++ni)
            bfr[ni] = *(const bf16x8*)&Bs[(wc * 64 + ni * 16 + l15) * 32 + quad * 8];
#pragma unroll
        for (int mi = 0; mi < 4; ++mi)
#pragma unroll
            for (int ni = 0; ni < 4; ++ni)
                acc[mi][ni] = __builtin_amdgcn_mfma_f32_16x16x32_bf16(af[mi], bfr[ni], acc[mi][ni], 0, 0, 0);
        __syncthreads();
    }

    // epilogue: write logits + accumulate per-row sum(exp(logit))
    int   ncol[4];
    float bo[4];
    bool  nv[4];
#pragma unroll
    for (int ni = 0; ni < 4; ++ni) {
        int n = n0 + wc * 64 + ni * 16 + l15;
        ncol[ni] = n;
        nv[ni] = (n < V_DIM);
        bo[ni] = nv[ni] ? b_out[n] : 0.f;
    }
#pragma unroll
    for (int mi = 0; mi < 4; ++mi)
#pragma unroll
        for (int r = 0; r < 4; ++r) {
            int m = m0 + wr * 64 + mi * 16 + quad * 4 + r;
            float s = 0.f;
#pragma unroll
            for (int ni = 0; ni < 4; ++ni) {
                if (nv[ni]) {
                    float logit = acc[mi][ni][r] + bo[ni];
                    out[(size_t)m * V_DIM + ncol[ni]] = logit;
                    s += __expf(logit);        // logits are ~|0.5| max: no max-sub needed
                }
            }
#pragma unroll
            for (int off = 8; off; off >>= 1) s += __shfl_xor(s, off, 16);
            if (l15 == 0) atomicAdd(&rowsum[m], s);
        }
}

// ---------------- finalize: out -= log(rowsum[row]) in place ----------------
__global__ void finalize_ls(float* __restrict__ out, const float* __restrict__ rowsum) {
    int row = blockIdx.x, t = threadIdx.x;
    float lz = __logf(rowsum[row]);
    size_t base = (size_t)row * V_DIM;
    int head = (int)((4 - (base & 3)) & 3);
    if (t < head) out[base + t] -= lz;
    int nvec = (V_DIM - head) >> 2;
    float4* vp = (float4*)(out + base + head);
    for (int i = t; i < nvec; i += 256) {
        float4 v = vp[i];
        v.x -= lz; v.y -= lz; v.z -= lz; v.w -= lz;
        vp[i] = v;
    }
    int done = head + (nvec << 2);
    for (int i = done + t; i < V_DIM; i += 256) out[base + i] -= lz;
}

extern "C" void kernel_launch(void* const* d_in, const int* in_sizes, int n_in,
                              void* d_out, int out_size, void* d_ws, size_t ws_size,
                              hipStream_t stream) {
    const int*   sent  = (const int*)d_in[0];
    const float* emb   = (const float*)d_in[1];
    const float* w_ih  = (const float*)d_in[2];
    // d_in[3] = W_hh: unused (h0 == 0)
    const float* b_ih  = (const float*)d_in[4];
    const float* b_hh  = (const float*)d_in[5];
    const float* w_out = (const float*)d_in[6];
    const float* b_out = (const float*)d_in[7];
    float* out = (float*)d_out;

    char* ws = (char*)d_ws;
    float*          rowsum = (float*)ws;                                   // 16 KB
    unsigned short* xbf    = (unsigned short*)(ws + 16384);                // 8 MB
    unsigned short* wihbf  = (unsigned short*)(ws + 16384 + 8388608);      // 8 MB
    unsigned short* hbf    = (unsigned short*)(ws + 16384 + 2 * 8388608);  // 8 MB
    float*          gates  = (float*)(ws + 16384 + 3 * 8388608);           // 64 MB
    unsigned short* woutbf = (unsigned short*)(ws + 16384 + 3 * 8388608 + 67108864); // 98.25 MB

    hipMemsetAsync(rowsum, 0, L_TOK * sizeof(float), stream);
    cvt_wih<<<4096, 256, 0, stream>>>(w_ih, wihbf);
    gather_x<<<L_TOK, 256, 0, stream>>>(sent, emb, xbf);
    cvt_wout<<<V_PAD, 256, 0, stream>>>(w_out, woutbf);
    gemm_gates<<<dim3(32, 24), 256, 0, stream>>>(xbf, wihbf, b_ih, b_hh, gates);
    lstm_ew<<<L_TOK, 256, 0, stream>>>(gates, hbf);
    gemm_logits<<<dim3(32, 393), 256, 0, stream>>>(hbf, woutbf, b_out, out, rowsum);
    finalize_ls<<<L_TOK, 256, 0, stream>>>(out, rowsum);
}